// Round 13
// baseline (280.944 us; speedup 1.0000x reference)
//
#include <hip/hip_runtime.h>
#include <math.h>

typedef __bf16 bf16_t;
typedef __bf16 bf16x8 __attribute__((ext_vector_type(8)));
typedef __bf16 bf16x4 __attribute__((ext_vector_type(4)));
typedef float  f32x4  __attribute__((ext_vector_type(4)));
typedef float  f32x16 __attribute__((ext_vector_type(16)));

// Problem shape (fixed by setup_inputs)
constexpr int Bb  = 4;
constexpr int L   = 4096;
constexpr int Dm  = 2048;
constexpr int S   = 512;
constexpr int M   = Bb * L;        // 16384
constexpr int NP  = 2 * S + 1;     // 1025
constexpr int PST = 1024;          // params stride (Bmat 0..511, Cmat 512..1023)
constexpr int CL  = 32;            // scan chunk length
constexpr int NCH = L / CL;        // 128
constexpr int TL  = 8;             // conv time-chunk per thread
constexpr int NTC = L / TL;        // 512

#define AS1 __attribute__((address_space(1)))
#define AS3 __attribute__((address_space(3)))

// ---------------------------------------------------------------------------
// float -> bf16 (RNE) pure stream (x conversion)
// ---------------------------------------------------------------------------
__global__ __launch_bounds__(256)
void f2b_kernel(const float* __restrict__ in, bf16_t* __restrict__ out,
                long out8, long in_elems)
{
    long i = (long)blockIdx.x * 256 + threadIdx.x;
    if (i >= out8) return;
    long e = i * 8;
    bf16x8 o;
    if (e + 8 <= in_elems) {
        float4 v0 = *(const float4*)(in + e);
        float4 v1 = *(const float4*)(in + e + 4);
        o[0] = (bf16_t)v0.x; o[1] = (bf16_t)v0.y;
        o[2] = (bf16_t)v0.z; o[3] = (bf16_t)v0.w;
        o[4] = (bf16_t)v1.x; o[5] = (bf16_t)v1.y;
        o[6] = (bf16_t)v1.z; o[7] = (bf16_t)v1.w;
    } else {
        #pragma unroll
        for (int k = 0; k < 8; ++k)
            o[k] = (e + k < in_elems) ? (bf16_t)in[e + k] : (bf16_t)0.f;
    }
    *(bf16x8*)(out + e) = o;
}

// ---------------------------------------------------------------------------
// All three weight conversions in ONE launch (ranges in 8-elem units):
// [0, 262144) Wx(PST*Dm), [262144, 393216) Win(S*Dm), [393216, 524288) Wout
// ---------------------------------------------------------------------------
__global__ __launch_bounds__(256)
void wcvt_kernel(const float* __restrict__ Wx, const float* __restrict__ Wi,
                 const float* __restrict__ Wo,
                 bf16_t* __restrict__ oWx, bf16_t* __restrict__ oWi,
                 bf16_t* __restrict__ oWo)
{
    long i = (long)blockIdx.x * 256 + threadIdx.x;
    const float* src; bf16_t* dst; long off;
    if (i < 262144L)      { src = Wx; dst = oWx; off = i; }
    else if (i < 393216L) { src = Wi; dst = oWi; off = i - 262144L; }
    else                  { src = Wo; dst = oWo; off = i - 393216L; }
    long e = off * 8;
    float4 v0 = *(const float4*)(src + e);
    float4 v1 = *(const float4*)(src + e + 4);
    bf16x8 o;
    o[0] = (bf16_t)v0.x; o[1] = (bf16_t)v0.y;
    o[2] = (bf16_t)v0.z; o[3] = (bf16_t)v0.w;
    o[4] = (bf16_t)v1.x; o[5] = (bf16_t)v1.y;
    o[6] = (bf16_t)v1.z; o[7] = (bf16_t)v1.w;
    *(bf16x8*)(dst + e) = o;
}

// ---------------------------------------------------------------------------
// Causal depthwise conv on bf16 x + fused delta partial-dot.
// ---------------------------------------------------------------------------
__global__ __launch_bounds__(256)
void conv_bf8(const bf16_t* __restrict__ xb, const float* __restrict__ w,
              const float* __restrict__ bias, const float* __restrict__ wdt,
              bf16_t* __restrict__ xcb, float* __restrict__ dpart)
{
    int g    = blockIdx.x * 256 + threadIdx.x;
    int d8   = g & 255;
    int rest = g >> 8;
    int c    = rest & (NTC - 1);
    int b    = rest >> 9;
    int d    = d8 * 8;
    int wv   = threadIdx.x >> 6;
    int lane = threadIdx.x & 63;

    float wv8[8][4];
    #pragma unroll
    for (int j = 0; j < 8; ++j)
        *(float4*)wv8[j] = *(const float4*)&w[(d + j) * 4];
    float bias8[8];
    *(float4*)&bias8[0] = *(const float4*)&bias[d];
    *(float4*)&bias8[4] = *(const float4*)&bias[d + 4];
    float wdt8[8];
    *(float4*)&wdt8[0] = *(const float4*)&wdt[d];
    *(float4*)&wdt8[4] = *(const float4*)&wdt[d + 4];

    const int l0 = c * TL;
    const size_t rowbase = (size_t)b * L;

    bf16x8 win[3];
    #pragma unroll
    for (int i = 0; i < 3; ++i) {
        int lp = l0 - 3 + i;
        if (lp >= 0) {
            win[i] = *(const bf16x8*)(xb + (rowbase + lp) * Dm + d);
        } else {
            #pragma unroll
            for (int j = 0; j < 8; ++j) win[i][j] = (bf16_t)0.f;
        }
    }

    float pd[TL];
    #pragma unroll
    for (int t = 0; t < TL; ++t) {
        size_t ri = (rowbase + l0 + t) * Dm + d;
        bf16x8 cur = *(const bf16x8*)(xb + ri);
        bf16x8 oc;
        float p = 0.f;
        #pragma unroll
        for (int j = 0; j < 8; ++j) {
            float cj = (float)cur[j];
            float a = bias8[j];
            a = fmaf((float)win[0][j], wv8[j][0], a);
            a = fmaf((float)win[1][j], wv8[j][1], a);
            a = fmaf((float)win[2][j], wv8[j][2], a);
            a = fmaf(cj,               wv8[j][3], a);
            oc[j] = (bf16_t)a;
            p = fmaf(cj, wdt8[j], p);
        }
        *(bf16x8*)(xcb + ri) = oc;
        pd[t] = p;
        win[0] = win[1]; win[1] = win[2]; win[2] = cur;
    }

    #pragma unroll
    for (int t = 0; t < TL; ++t) {
        float s = pd[t];
        #pragma unroll
        for (int off = 32; off >= 1; off >>= 1) s += __shfl_xor(s, off, 64);
        pd[t] = s;
    }
    if (lane == 0) {
        int mbase = b * L + l0;
        #pragma unroll
        for (int t = 0; t < TL; ++t)
            dpart[(size_t)(mbase + t) * 4 + wv] = pd[t];
    }
}

// ---------------------------------------------------------------------------
// delta[m] = softplus( sum of 4 wave partials )
// ---------------------------------------------------------------------------
__global__ __launch_bounds__(256)
void delta_reduce(const float* __restrict__ dpart, float* __restrict__ delta)
{
    int i = blockIdx.x * 256 + threadIdx.x;
    if (i < M) {
        float4 p = *(const float4*)(dpart + (size_t)i * 4);
        float z = (p.x + p.y) + (p.z + p.w);
        delta[i] = (z > 20.f) ? z : log1pf(__expf(z));
    }
}

// ---------------------------------------------------------------------------
// Shared GEMM machinery: XOR-swizzled LDS regions of R rows x 64 cols bf16,
// (R,k) at R*64 + (k ^ ((R&7)<<3)); global SOURCE inverse-swizzled (rule #21).
// ---------------------------------------------------------------------------
__device__ __forceinline__ void stage_slabA(const bf16_t* __restrict__ A,
    bf16_t* lds, int ldsbase, int row0, int K, int kcol, int mh,
    int wid, int lrow, int cswz)
{
    #pragma unroll
    for (int round = 0; round < 2; ++round) {
        int Rb = round * 128 + mh * 64 + wid * 8;
        const bf16_t* src = A + (size_t)(row0 + Rb + lrow) * K + kcol + cswz;
        __builtin_amdgcn_global_load_lds(
            (AS1 void*)src, (AS3 void*)(lds + ldsbase + Rb * 64), 16, 0, 0);
    }
}

// 128-row A slab, 512 threads (2 loads/thread)
__device__ __forceinline__ void stage_slabA128(const bf16_t* __restrict__ A,
    bf16_t* lds, int ldsbase, int row0, int K, int kcol,
    int wid, int lrow, int cswz)
{
    #pragma unroll
    for (int round = 0; round < 2; ++round) {
        int Rb = round * 64 + wid * 8;
        const bf16_t* src = A + (size_t)(row0 + Rb + lrow) * K + kcol + cswz;
        __builtin_amdgcn_global_load_lds(
            (AS1 void*)src, (AS3 void*)(lds + ldsbase + Rb * 64), 16, 0, 0);
    }
}

__device__ __forceinline__ void stage_slabB(const bf16_t* __restrict__ B,
    bf16_t* lds, int ldsbase, int col0, int K, int kcol, int nh,
    int wid, int lrow, int cswz)
{
    #pragma unroll
    for (int round = 0; round < 2; ++round) {
        int c  = round * 8 + wid;
        int Rb = (c >> 2) * 64 + nh * 32 + (c & 3) * 8;
        const bf16_t* src = B + (size_t)(col0 + Rb + lrow) * K + kcol + cswz;
        __builtin_amdgcn_global_load_lds(
            (AS1 void*)src, (AS3 void*)(lds + ldsbase + Rb * 64), 16, 0, 0);
    }
}

template <int MH>
__device__ __forceinline__ void load_fragsA32(const bf16_t* lds, int Abase,
    int wm, int l31, int kh, bf16x8 (&af)[2][4])
{
    #pragma unroll
    for (int mi2 = 0; mi2 < 2; ++mi2) {
        const int R = wm * 128 + (MH * 2 + mi2) * 32 + l31;
        #pragma unroll
        for (int ks = 0; ks < 4; ++ks)
            af[mi2][ks] = *(const bf16x8*)(lds + Abase + R * 64 +
                            ((ks * 16 + kh * 8) ^ ((R & 7) << 3)));
    }
}

template <int MI>
__device__ __forceinline__ void load_fragsA32h(const bf16_t* lds, int Abase,
    int wm, int l31, int kh, bf16x8 (&af)[4])
{
    const int R = wm * 64 + MI * 32 + l31;
    #pragma unroll
    for (int ks = 0; ks < 4; ++ks)
        af[ks] = *(const bf16x8*)(lds + Abase + R * 64 +
                    ((ks * 16 + kh * 8) ^ ((R & 7) << 3)));
}

template <int NH>
__device__ __forceinline__ void load_fragsB32(const bf16_t* lds, int Bbase,
    int wn, int l31, int kh, bf16x8 (&bfr)[4])
{
    const int R = wn * 64 + NH * 32 + l31;
    #pragma unroll
    for (int ks = 0; ks < 4; ++ks)
        bfr[ks] = *(const bf16x8*)(lds + Bbase + R * 64 +
                    ((ks * 16 + kh * 8) ^ ((R & 7) << 3)));
}

template <int MH, int NH>
__device__ __forceinline__ void do_mfma32(bf16x8 (&af)[2][4], bf16x8 (&bfr)[4],
                                          f32x16 (&acc)[4][2])
{
    __builtin_amdgcn_s_setprio(1);
    #pragma unroll
    for (int ks = 0; ks < 4; ++ks)
        #pragma unroll
        for (int mi2 = 0; mi2 < 2; ++mi2)
            acc[MH * 2 + mi2][NH] = __builtin_amdgcn_mfma_f32_32x32x16_bf16(
                af[mi2][ks], bfr[ks], acc[MH * 2 + mi2][NH], 0, 0, 0);
    __builtin_amdgcn_s_setprio(0);
}

template <int MI, int NJ>
__device__ __forceinline__ void do_mfma32h(bf16x8 (&af)[4], bf16x8 (&bfr)[4],
                                           f32x16 (&acc)[2][2])
{
    __builtin_amdgcn_s_setprio(1);
    #pragma unroll
    for (int ks = 0; ks < 4; ++ks)
        acc[MI][NJ] = __builtin_amdgcn_mfma_f32_32x32x16_bf16(
            af[ks], bfr[ks], acc[MI][NJ], 0, 0, 0);
    __builtin_amdgcn_s_setprio(0);
}

#define WAITBAR(N) do { \
    asm volatile("s_waitcnt vmcnt(" #N ")" ::: "memory"); \
    __builtin_amdgcn_s_barrier(); } while (0)

// ---------------------------------------------------------------------------
// 256x256 tile, BK=64, 8 waves (2x4), 4-phase counted-vmcnt schedule.
// EPI 0 (params): bf16 Cb[m*PST+n]
// ---------------------------------------------------------------------------
template <int EPI>
__global__ __launch_bounds__(512, 2)
void gemm8p(const bf16_t* __restrict__ A, const bf16_t* __restrict__ B,
            int N, int K, int NT,
            bf16_t* __restrict__ Cb, float* __restrict__ Cf,
            const float* __restrict__ e0, const bf16_t* __restrict__ eb)
{
    extern __shared__ __align__(16) char smem_raw[];
    bf16_t* lds = (bf16_t*)smem_raw;

    const int tid  = threadIdx.x;
    const int lane = tid & 63;
    const int wid  = tid >> 6;
    const int wm   = wid >> 2;
    const int wn   = wid & 3;
    const int l31  = lane & 31;
    const int kh   = lane >> 5;
    const int row0 = blockIdx.x * 256;
    const int col0 = blockIdx.y * 256;
    const int lrow = lane >> 3;
    const int cswz = 8 * ((lane & 7) ^ lrow);

    f32x16 acc[4][2];
    #pragma unroll
    for (int i = 0; i < 4; ++i)
        #pragma unroll
        for (int j = 0; j < 2; ++j)
            #pragma unroll
            for (int g = 0; g < 16; ++g) acc[i][j][g] = 0.f;

    stage_slabA(A, lds, 0,     row0, K, 0, 0, wid, lrow, cswz);
    stage_slabB(B, lds, 16384, col0, K, 0, 0, wid, lrow, cswz);
    stage_slabB(B, lds, 16384, col0, K, 0, 1, wid, lrow, cswz);
    stage_slabA(A, lds, 0,     row0, K, 0, 1, wid, lrow, cswz);

    for (int kt = 0; kt < NT; ++kt) {
        const int cur = kt & 1, nxt = cur ^ 1;
        const int Abase = cur * 32768, Bbase = cur * 32768 + 16384;
        const int An = nxt * 32768,   Bn = nxt * 32768 + 16384;
        const int kc = (kt + 1 < NT ? kt + 1 : kt) * 64;

        bf16x8 af[2][4], bfr[4];

        WAITBAR(4);
        load_fragsA32<0>(lds, Abase, wm, l31, kh, af);
        load_fragsB32<0>(lds, Bbase, wn, l31, kh, bfr);
        stage_slabA(A, lds, An, row0, K, kc, 0, wid, lrow, cswz);
        do_mfma32<0, 0>(af, bfr, acc);

        WAITBAR(4);
        load_fragsB32<1>(lds, Bbase, wn, l31, kh, bfr);
        stage_slabB(B, lds, Bn, col0, K, kc, 0, wid, lrow, cswz);
        do_mfma32<0, 1>(af, bfr, acc);

        WAITBAR(4);
        load_fragsA32<1>(lds, Abase, wm, l31, kh, af);
        stage_slabB(B, lds, Bn, col0, K, kc, 1, wid, lrow, cswz);
        do_mfma32<1, 1>(af, bfr, acc);

        load_fragsB32<0>(lds, Bbase, wn, l31, kh, bfr);
        stage_slabA(A, lds, An, row0, K, kc, 1, wid, lrow, cswz);
        do_mfma32<1, 0>(af, bfr, acc);
    }

    // epilogue: 32x32 D map col=lane&31, row=(rg&3)+8*(rg>>2)+4*(lane>>5)
    #pragma unroll
    for (int mi = 0; mi < 4; ++mi) {
        #pragma unroll
        for (int nj = 0; nj < 2; ++nj) {
            #pragma unroll
            for (int rg = 0; rg < 16; ++rg) {
                int mr = row0 + wm * 128 + mi * 32 + (rg & 3) + 8 * (rg >> 2) + 4 * kh;
                int nc = col0 + wn * 64 + nj * 32 + l31;
                float v = acc[mi][nj][rg];
                if (EPI == 0) {
                    Cb[(size_t)mr * PST + nc] = (bf16_t)v;
                } else {
                    float xc = (float)eb[(size_t)mr * N + nc];
                    Cf[(size_t)mr * N + nc] = v + e0[nc] * xc;
                }
            }
        }
    }
}

// ---------------------------------------------------------------------------
// 128x256 tile (GEMM2), BK=64, 8 waves 2x4, counted-vmcnt(2); Bu bf16 epilogue.
// ---------------------------------------------------------------------------
__global__ __launch_bounds__(512, 2)
void gemm8ph(const bf16_t* __restrict__ A, const bf16_t* __restrict__ B,
             int N, int K, int NT,
             bf16_t* __restrict__ Bub,
             const float* __restrict__ e0, const bf16_t* __restrict__ eb)
{
    extern __shared__ __align__(16) char smem_raw[];
    bf16_t* lds = (bf16_t*)smem_raw;

    const int tid  = threadIdx.x;
    const int lane = tid & 63;
    const int wid  = tid >> 6;
    const int wm   = wid >> 2;
    const int wn   = wid & 3;
    const int l31  = lane & 31;
    const int kh   = lane >> 5;
    const int row0 = blockIdx.x * 128;
    const int col0 = blockIdx.y * 256;
    const int lrow = lane >> 3;
    const int cswz = 8 * ((lane & 7) ^ lrow);

    f32x16 acc[2][2];
    #pragma unroll
    for (int i = 0; i < 2; ++i)
        #pragma unroll
        for (int j = 0; j < 2; ++j)
            #pragma unroll
            for (int g = 0; g < 16; ++g) acc[i][j][g] = 0.f;

    stage_slabA128(A, lds, 0,    row0, K, 0, wid, lrow, cswz);
    stage_slabB(B, lds, 8192, col0, K, 0, 0, wid, lrow, cswz);
    stage_slabB(B, lds, 8192, col0, K, 0, 1, wid, lrow, cswz);

    for (int kt = 0; kt < NT; ++kt) {
        const int cur = kt & 1, nxt = cur ^ 1;
        const int Abase = cur * 24576, Bbase = cur * 24576 + 8192;
        const int An = nxt * 24576,   Bn = nxt * 24576 + 8192;
        const int kc = (kt + 1 < NT ? kt + 1 : kt) * 64;

        bf16x8 af[4], bfr[4];

        WAITBAR(2);
        load_fragsA32h<0>(lds, Abase, wm, l31, kh, af);
        load_fragsB32<0>(lds, Bbase, wn, l31, kh, bfr);
        stage_slabA128(A, lds, An, row0, K, kc, wid, lrow, cswz);
        do_mfma32h<0, 0>(af, bfr, acc);

        WAITBAR(2);
        load_fragsB32<1>(lds, Bbase, wn, l31, kh, bfr);
        stage_slabB(B, lds, Bn, col0, K, kc, 0, wid, lrow, cswz);
        do_mfma32h<0, 1>(af, bfr, acc);

        load_fragsA32h<1>(lds, Abase, wm, l31, kh, af);
        stage_slabB(B, lds, Bn, col0, K, kc, 1, wid, lrow, cswz);
        do_mfma32h<1, 1>(af, bfr, acc);

        load_fragsB32<0>(lds, Bbase, wn, l31, kh, bfr);
        do_mfma32h<1, 0>(af, bfr, acc);
    }

    #pragma unroll
    for (int mi = 0; mi < 2; ++mi) {
        #pragma unroll
        for (int nj = 0; nj < 2; ++nj) {
            #pragma unroll
            for (int rg = 0; rg < 16; ++rg) {
                int mr = row0 + wm * 64 + mi * 32 + (rg & 3) + 8 * (rg >> 2) + 4 * kh;
                int nc = col0 + wn * 64 + nj * 32 + l31;
                float Bm = (float)eb[(size_t)mr * PST + nc];
                Bub[(size_t)mr * N + nc] = (bf16_t)(e0[mr] * Bm * acc[mi][nj][rg]);
            }
        }
    }
}

// ---------------------------------------------------------------------------
// GEMM3 via the SAME verified 128x256 counted-vmcnt schedule (gemm8ph clone),
// fp32-out epilogue: out[m*N+n] = acc + e0[n] * bf2f(eb[m*N+n]).
// Grid (M/128, Dm/256) = 128x8 = 1024 blocks -> 4 block-rounds/CU, store
// drain of finishing blocks overlaps prologue loads of incoming blocks.
// ---------------------------------------------------------------------------
__global__ __launch_bounds__(512, 2)
void gemm8pf(const bf16_t* __restrict__ A, const bf16_t* __restrict__ B,
             int N, int K, int NT,
             float* __restrict__ Cf,
             const float* __restrict__ e0, const bf16_t* __restrict__ eb)
{
    extern __shared__ __align__(16) char smem_raw[];
    bf16_t* lds = (bf16_t*)smem_raw;

    const int tid  = threadIdx.x;
    const int lane = tid & 63;
    const int wid  = tid >> 6;
    const int wm   = wid >> 2;
    const int wn   = wid & 3;
    const int l31  = lane & 31;
    const int kh   = lane >> 5;
    const int row0 = blockIdx.x * 128;
    const int col0 = blockIdx.y * 256;
    const int lrow = lane >> 3;
    const int cswz = 8 * ((lane & 7) ^ lrow);

    f32x16 acc[2][2];
    #pragma unroll
    for (int i = 0; i < 2; ++i)
        #pragma unroll
        for (int j = 0; j < 2; ++j)
            #pragma unroll
            for (int g = 0; g < 16; ++g) acc[i][j][g] = 0.f;

    stage_slabA128(A, lds, 0,    row0, K, 0, wid, lrow, cswz);
    stage_slabB(B, lds, 8192, col0, K, 0, 0, wid, lrow, cswz);
    stage_slabB(B, lds, 8192, col0, K, 0, 1, wid, lrow, cswz);

    for (int kt = 0; kt < NT; ++kt) {
        const int cur = kt & 1, nxt = cur ^ 1;
        const int Abase = cur * 24576, Bbase = cur * 24576 + 8192;
        const int An = nxt * 24576,   Bn = nxt * 24576 + 8192;
        const int kc = (kt + 1 < NT ? kt + 1 : kt) * 64;

        bf16x8 af[4], bfr[4];

        WAITBAR(2);
        load_fragsA32h<0>(lds, Abase, wm, l31, kh, af);
        load_fragsB32<0>(lds, Bbase, wn, l31, kh, bfr);
        stage_slabA128(A, lds, An, row0, K, kc, wid, lrow, cswz);
        do_mfma32h<0, 0>(af, bfr, acc);

        WAITBAR(2);
        load_fragsB32<1>(lds, Bbase, wn, l31, kh, bfr);
        stage_slabB(B, lds, Bn, col0, K, kc, 0, wid, lrow, cswz);
        do_mfma32h<0, 1>(af, bfr, acc);

        load_fragsA32h<1>(lds, Abase, wm, l31, kh, af);
        stage_slabB(B, lds, Bn, col0, K, kc, 1, wid, lrow, cswz);
        do_mfma32h<1, 1>(af, bfr, acc);

        load_fragsB32<0>(lds, Bbase, wn, l31, kh, bfr);
        do_mfma32h<1, 0>(af, bfr, acc);
    }

    #pragma unroll
    for (int mi = 0; mi < 2; ++mi) {
        #pragma unroll
        for (int nj = 0; nj < 2; ++nj) {
            #pragma unroll
            for (int rg = 0; rg < 16; ++rg) {
                int mr = row0 + wm * 64 + mi * 32 + (rg & 3) + 8 * (rg >> 2) + 4 * kh;
                int nc = col0 + wn * 64 + nj * 32 + l31;
                float xc = (float)eb[(size_t)mr * N + nc];
                Cf[(size_t)mr * N + nc] = acc[mi][nj][rg] + e0[nc] * xc;
            }
        }
    }
}

// ---------------------------------------------------------------------------
// chunked scan: h[l] = a[l]*h[l-1] + u[l],  a = exp(-exp(A_log[s]) * delta[l])
// ---------------------------------------------------------------------------
__global__ __launch_bounds__(256)
void scan_pass1(const bf16_t* __restrict__ Bu, const float* __restrict__ delta,
                const float* __restrict__ A_log,
                float* __restrict__ cP, float* __restrict__ cH)
{
    int s = blockIdx.x * 256 + threadIdx.x;
    int c = blockIdx.y;
    int b = blockIdx.z;
    float Acoef = -expf(A_log[s]);
    float P = 1.f, h = 0.f;
    int mbase = b * L + c * CL;
    for (int t = 0; t < CL; ++t) {
        float a = __expf(Acoef * delta[mbase + t]);
        float u = (float)Bu[(size_t)(mbase + t) * S + s];
        h = fmaf(a, h, u);
        P *= a;
    }
    int id = b * S + s;
    cP[(size_t)id * NCH + c] = P;
    cH[(size_t)id * NCH + c] = h;
}

__global__ __launch_bounds__(256)
void scan_pass2(const float* __restrict__ cP, const float* __restrict__ cH,
                float* __restrict__ init)
{
    int id = blockIdx.x * 256 + threadIdx.x;
    if (id < Bb * S) {
        float h = 0.f;
        for (int c = 0; c < NCH; ++c) {
            init[(size_t)id * NCH + c] = h;
            h = fmaf(cP[(size_t)id * NCH + c], h, cH[(size_t)id * NCH + c]);
        }
    }
}

__global__ __launch_bounds__(256)
void scan_pass3(const bf16_t* __restrict__ Bu, const float* __restrict__ delta,
                const bf16_t* __restrict__ params_bf,
                const float* __restrict__ A_log,
                const float* __restrict__ init, bf16_t* __restrict__ hmod)
{
    int s = blockIdx.x * 256 + threadIdx.x;
    int c = blockIdx.y;
    int b = blockIdx.z;
    float Acoef = -expf(A_log[s]);
    float h = init[(size_t)(b * S + s) * NCH + c];
    int mbase = b * L + c * CL;
    for (int t = 0; t < CL; ++t) {
        int m = mbase + t;
        float a = __expf(Acoef * delta[m]);
        float u = (float)Bu[(size_t)m * S + s];
        h = fmaf(a, h, u);
        float Cm = (float)params_bf[(size_t)m * PST + S + s];
        hmod[(size_t)m * S + s] = (bf16_t)(Cm * h);
    }
}

// ---------------------------------------------------------------------------
extern "C" void kernel_launch(void* const* d_in, const int* in_sizes, int n_in,
                              void* d_out, int out_size, void* d_ws, size_t ws_size,
                              hipStream_t stream)
{
    const float* x        = (const float*)d_in[0];
    const float* Wxproj   = (const float*)d_in[1];
    const float* Winproj  = (const float*)d_in[2];
    const float* Woutproj = (const float*)d_in[3];
    const float* conv_w   = (const float*)d_in[4];
    const float* conv_b   = (const float*)d_in[5];
    const float* A_log    = (const float*)d_in[6];
    const float* Dvec     = (const float*)d_in[7];
    float* out = (float*)d_out;

    // fp32 workspace
    float* ws_delta = (float*)d_ws;                       // M
    float* ws_dpart = ws_delta + M;                       // M*4
    float* ws_cP    = ws_dpart + (size_t)M * 4;           // Bb*S*NCH
    float* ws_cH    = ws_cP + (size_t)Bb * S * NCH;
    float* ws_init  = ws_cH + (size_t)Bb * S * NCH;
    // bf16 workspace
    bf16_t* Bu_bf     = (bf16_t*)(ws_init + (size_t)Bb * S * NCH); // M*S
    bf16_t* params_bf = Bu_bf + (size_t)M * S;            // M*PST
    bf16_t* x_bf      = params_bf + (size_t)M * PST;      // M*Dm
    bf16_t* hmod_bf   = x_bf;                             // M*S (alias; x_bf dead after GEMM1)
    bf16_t* xconv_bf  = x_bf + (size_t)M * Dm;            // M*Dm
    bf16_t* Wx_bf     = xconv_bf + (size_t)M * Dm;        // PST*Dm
    bf16_t* Win_bf    = Wx_bf + (size_t)PST * Dm;         // S*Dm
    bf16_t* Wout_bf   = Win_bf + (size_t)S * Dm;          // Dm*S

    hipFuncSetAttribute((const void*)gemm8p<0>,
                        hipFuncAttributeMaxDynamicSharedMemorySize, 131072);
    hipFuncSetAttribute((const void*)gemm8ph,
                        hipFuncAttributeMaxDynamicSharedMemorySize, 98304);
    hipFuncSetAttribute((const void*)gemm8pf,
                        hipFuncAttributeMaxDynamicSharedMemorySize, 98304);

    // 1. x -> bf16 (pure stream)
    long x8 = (long)M * Dm / 8;
    f2b_kernel<<<(x8 + 255) / 256, 256, 0, stream>>>(x, x_bf, x8, (long)M * Dm);

    // 2. all weight conversions in one launch (524288 8-elem units)
    wcvt_kernel<<<2048, 256, 0, stream>>>(Wxproj, Winproj, Woutproj,
                                          Wx_bf, Win_bf, Wout_bf);

    // 3. conv on bf16 x + fused delta partial dot
    conv_bf8<<<Bb * NTC, 256, 0, stream>>>(
        x_bf, conv_w, conv_b, Wxproj + (size_t)(2 * S) * Dm, xconv_bf, ws_dpart);

    // 4. delta = softplus(sum of partials)
    delta_reduce<<<M / 256, 256, 0, stream>>>(ws_dpart, ws_delta);

    // 5. GEMM1: params(bf16, stride 1024) = x @ Wxproj[0:1024]^T
    dim3 g1(M / 256, PST / 256);
    gemm8p<0><<<g1, 512, 131072, stream>>>(x_bf, Wx_bf, PST, Dm, Dm / 64,
                                           params_bf, nullptr, nullptr, nullptr);

    // 6. GEMM2: Bu(bf16) = delta * Bmat * (x_conv @ Winproj^T)
    dim3 g2(M / 128, S / 256);
    gemm8ph<<<g2, 512, 98304, stream>>>(xconv_bf, Win_bf, S, Dm, Dm / 64,
                                        Bu_bf, ws_delta, params_bf);

    // 7. chunked scan; h_mod = Cmat*h -> bf16
    dim3 gs(S / 256, NCH, Bb);
    scan_pass1<<<gs, 256, 0, stream>>>(Bu_bf, ws_delta, A_log, ws_cP, ws_cH);
    scan_pass2<<<(Bb * S) / 256, 256, 0, stream>>>(ws_cP, ws_cH, ws_init);
    scan_pass3<<<gs, 256, 0, stream>>>(Bu_bf, ws_delta, params_bf, A_log,
                                       ws_init, hmod_bf);

    // 8. GEMM3: out = h_mod @ Woutproj^T + D * x_conv   (verified gemm8ph schedule)
    dim3 g3(M / 128, Dm / 256);
    gemm8pf<<<g3, 512, 98304, stream>>>(hmod_bf, Wout_bf, Dm, S, S / 64,
                                        out, Dvec, xconv_bf);
}

// Round 15
// 269.495 us; speedup vs baseline: 1.0425x; 1.0425x over previous
//
#include <hip/hip_runtime.h>
#include <math.h>

typedef __bf16 bf16_t;
typedef __bf16 bf16x8 __attribute__((ext_vector_type(8)));
typedef __bf16 bf16x4 __attribute__((ext_vector_type(4)));
typedef float  f32x4  __attribute__((ext_vector_type(4)));
typedef float  f32x16 __attribute__((ext_vector_type(16)));

// Problem shape (fixed by setup_inputs)
constexpr int Bb  = 4;
constexpr int L   = 4096;
constexpr int Dm  = 2048;
constexpr int S   = 512;
constexpr int M   = Bb * L;        // 16384
constexpr int NP  = 2 * S + 1;     // 1025
constexpr int PST = 1024;          // params stride (Bmat 0..511, Cmat 512..1023)
constexpr int CL  = 32;            // scan chunk length
constexpr int NCH = L / CL;        // 128
constexpr int TL  = 8;             // conv time-chunk per thread
constexpr int NTC = L / TL;        // 512

#define AS1 __attribute__((address_space(1)))
#define AS3 __attribute__((address_space(3)))

// ---------------------------------------------------------------------------
// float -> bf16 (RNE) pure stream (x conversion)
// ---------------------------------------------------------------------------
__global__ __launch_bounds__(256)
void f2b_kernel(const float* __restrict__ in, bf16_t* __restrict__ out,
                long out8, long in_elems)
{
    long i = (long)blockIdx.x * 256 + threadIdx.x;
    if (i >= out8) return;
    long e = i * 8;
    bf16x8 o;
    if (e + 8 <= in_elems) {
        float4 v0 = *(const float4*)(in + e);
        float4 v1 = *(const float4*)(in + e + 4);
        o[0] = (bf16_t)v0.x; o[1] = (bf16_t)v0.y;
        o[2] = (bf16_t)v0.z; o[3] = (bf16_t)v0.w;
        o[4] = (bf16_t)v1.x; o[5] = (bf16_t)v1.y;
        o[6] = (bf16_t)v1.z; o[7] = (bf16_t)v1.w;
    } else {
        #pragma unroll
        for (int k = 0; k < 8; ++k)
            o[k] = (e + k < in_elems) ? (bf16_t)in[e + k] : (bf16_t)0.f;
    }
    *(bf16x8*)(out + e) = o;
}

// ---------------------------------------------------------------------------
// All three weight conversions in ONE launch (ranges in 8-elem units)
// ---------------------------------------------------------------------------
__global__ __launch_bounds__(256)
void wcvt_kernel(const float* __restrict__ Wx, const float* __restrict__ Wi,
                 const float* __restrict__ Wo,
                 bf16_t* __restrict__ oWx, bf16_t* __restrict__ oWi,
                 bf16_t* __restrict__ oWo)
{
    long i = (long)blockIdx.x * 256 + threadIdx.x;
    const float* src; bf16_t* dst; long off;
    if (i < 262144L)      { src = Wx; dst = oWx; off = i; }
    else if (i < 393216L) { src = Wi; dst = oWi; off = i - 262144L; }
    else                  { src = Wo; dst = oWo; off = i - 393216L; }
    long e = off * 8;
    float4 v0 = *(const float4*)(src + e);
    float4 v1 = *(const float4*)(src + e + 4);
    bf16x8 o;
    o[0] = (bf16_t)v0.x; o[1] = (bf16_t)v0.y;
    o[2] = (bf16_t)v0.z; o[3] = (bf16_t)v0.w;
    o[4] = (bf16_t)v1.x; o[5] = (bf16_t)v1.y;
    o[6] = (bf16_t)v1.z; o[7] = (bf16_t)v1.w;
    *(bf16x8*)(dst + e) = o;
}

// ---------------------------------------------------------------------------
// Causal depthwise conv on bf16 x + fused delta partial-dot.
// ---------------------------------------------------------------------------
__global__ __launch_bounds__(256)
void conv_bf8(const bf16_t* __restrict__ xb, const float* __restrict__ w,
              const float* __restrict__ bias, const float* __restrict__ wdt,
              bf16_t* __restrict__ xcb, float* __restrict__ dpart)
{
    int g    = blockIdx.x * 256 + threadIdx.x;
    int d8   = g & 255;
    int rest = g >> 8;
    int c    = rest & (NTC - 1);
    int b    = rest >> 9;
    int d    = d8 * 8;
    int wv   = threadIdx.x >> 6;
    int lane = threadIdx.x & 63;

    float wv8[8][4];
    #pragma unroll
    for (int j = 0; j < 8; ++j)
        *(float4*)wv8[j] = *(const float4*)&w[(d + j) * 4];
    float bias8[8];
    *(float4*)&bias8[0] = *(const float4*)&bias[d];
    *(float4*)&bias8[4] = *(const float4*)&bias[d + 4];
    float wdt8[8];
    *(float4*)&wdt8[0] = *(const float4*)&wdt[d];
    *(float4*)&wdt8[4] = *(const float4*)&wdt[d + 4];

    const int l0 = c * TL;
    const size_t rowbase = (size_t)b * L;

    bf16x8 win[3];
    #pragma unroll
    for (int i = 0; i < 3; ++i) {
        int lp = l0 - 3 + i;
        if (lp >= 0) {
            win[i] = *(const bf16x8*)(xb + (rowbase + lp) * Dm + d);
        } else {
            #pragma unroll
            for (int j = 0; j < 8; ++j) win[i][j] = (bf16_t)0.f;
        }
    }

    float pd[TL];
    #pragma unroll
    for (int t = 0; t < TL; ++t) {
        size_t ri = (rowbase + l0 + t) * Dm + d;
        bf16x8 cur = *(const bf16x8*)(xb + ri);
        bf16x8 oc;
        float p = 0.f;
        #pragma unroll
        for (int j = 0; j < 8; ++j) {
            float cj = (float)cur[j];
            float a = bias8[j];
            a = fmaf((float)win[0][j], wv8[j][0], a);
            a = fmaf((float)win[1][j], wv8[j][1], a);
            a = fmaf((float)win[2][j], wv8[j][2], a);
            a = fmaf(cj,               wv8[j][3], a);
            oc[j] = (bf16_t)a;
            p = fmaf(cj, wdt8[j], p);
        }
        *(bf16x8*)(xcb + ri) = oc;
        pd[t] = p;
        win[0] = win[1]; win[1] = win[2]; win[2] = cur;
    }

    #pragma unroll
    for (int t = 0; t < TL; ++t) {
        float s = pd[t];
        #pragma unroll
        for (int off = 32; off >= 1; off >>= 1) s += __shfl_xor(s, off, 64);
        pd[t] = s;
    }
    if (lane == 0) {
        int mbase = b * L + l0;
        #pragma unroll
        for (int t = 0; t < TL; ++t)
            dpart[(size_t)(mbase + t) * 4 + wv] = pd[t];
    }
}

// ---------------------------------------------------------------------------
// delta[m] = softplus( sum of 4 wave partials )
// ---------------------------------------------------------------------------
__global__ __launch_bounds__(256)
void delta_reduce(const float* __restrict__ dpart, float* __restrict__ delta)
{
    int i = blockIdx.x * 256 + threadIdx.x;
    if (i < M) {
        float4 p = *(const float4*)(dpart + (size_t)i * 4);
        float z = (p.x + p.y) + (p.z + p.w);
        delta[i] = (z > 20.f) ? z : log1pf(__expf(z));
    }
}

// ---------------------------------------------------------------------------
// Shared GEMM machinery: XOR-swizzled LDS regions of R rows x 64 cols bf16,
// (R,k) at R*64 + (k ^ ((R&7)<<3)); global SOURCE inverse-swizzled (rule #21).
// ---------------------------------------------------------------------------
__device__ __forceinline__ void stage_slabA(const bf16_t* __restrict__ A,
    bf16_t* lds, int ldsbase, int row0, int K, int kcol, int mh,
    int wid, int lrow, int cswz)
{
    #pragma unroll
    for (int round = 0; round < 2; ++round) {
        int Rb = round * 128 + mh * 64 + wid * 8;
        const bf16_t* src = A + (size_t)(row0 + Rb + lrow) * K + kcol + cswz;
        __builtin_amdgcn_global_load_lds(
            (AS1 void*)src, (AS3 void*)(lds + ldsbase + Rb * 64), 16, 0, 0);
    }
}

// 128-row A slab, 512 threads (2 loads/thread)
__device__ __forceinline__ void stage_slabA128(const bf16_t* __restrict__ A,
    bf16_t* lds, int ldsbase, int row0, int K, int kcol,
    int wid, int lrow, int cswz)
{
    #pragma unroll
    for (int round = 0; round < 2; ++round) {
        int Rb = round * 64 + wid * 8;
        const bf16_t* src = A + (size_t)(row0 + Rb + lrow) * K + kcol + cswz;
        __builtin_amdgcn_global_load_lds(
            (AS1 void*)src, (AS3 void*)(lds + ldsbase + Rb * 64), 16, 0, 0);
    }
}

__device__ __forceinline__ void stage_slabB(const bf16_t* __restrict__ B,
    bf16_t* lds, int ldsbase, int col0, int K, int kcol, int nh,
    int wid, int lrow, int cswz)
{
    #pragma unroll
    for (int round = 0; round < 2; ++round) {
        int c  = round * 8 + wid;
        int Rb = (c >> 2) * 64 + nh * 32 + (c & 3) * 8;
        const bf16_t* src = B + (size_t)(col0 + Rb + lrow) * K + kcol + cswz;
        __builtin_amdgcn_global_load_lds(
            (AS1 void*)src, (AS3 void*)(lds + ldsbase + Rb * 64), 16, 0, 0);
    }
}

template <int MH>
__device__ __forceinline__ void load_fragsA32(const bf16_t* lds, int Abase,
    int wm, int l31, int kh, bf16x8 (&af)[2][4])
{
    #pragma unroll
    for (int mi2 = 0; mi2 < 2; ++mi2) {
        const int R = wm * 128 + (MH * 2 + mi2) * 32 + l31;
        #pragma unroll
        for (int ks = 0; ks < 4; ++ks)
            af[mi2][ks] = *(const bf16x8*)(lds + Abase + R * 64 +
                            ((ks * 16 + kh * 8) ^ ((R & 7) << 3)));
    }
}

template <int MI>
__device__ __forceinline__ void load_fragsA32h(const bf16_t* lds, int Abase,
    int wm, int l31, int kh, bf16x8 (&af)[4])
{
    const int R = wm * 64 + MI * 32 + l31;
    #pragma unroll
    for (int ks = 0; ks < 4; ++ks)
        af[ks] = *(const bf16x8*)(lds + Abase + R * 64 +
                    ((ks * 16 + kh * 8) ^ ((R & 7) << 3)));
}

template <int NH>
__device__ __forceinline__ void load_fragsB32(const bf16_t* lds, int Bbase,
    int wn, int l31, int kh, bf16x8 (&bfr)[4])
{
    const int R = wn * 64 + NH * 32 + l31;
    #pragma unroll
    for (int ks = 0; ks < 4; ++ks)
        bfr[ks] = *(const bf16x8*)(lds + Bbase + R * 64 +
                    ((ks * 16 + kh * 8) ^ ((R & 7) << 3)));
}

template <int MH, int NH>
__device__ __forceinline__ void do_mfma32(bf16x8 (&af)[2][4], bf16x8 (&bfr)[4],
                                          f32x16 (&acc)[4][2])
{
    __builtin_amdgcn_s_setprio(1);
    #pragma unroll
    for (int ks = 0; ks < 4; ++ks)
        #pragma unroll
        for (int mi2 = 0; mi2 < 2; ++mi2)
            acc[MH * 2 + mi2][NH] = __builtin_amdgcn_mfma_f32_32x32x16_bf16(
                af[mi2][ks], bfr[ks], acc[MH * 2 + mi2][NH], 0, 0, 0);
    __builtin_amdgcn_s_setprio(0);
}

template <int MI, int NJ>
__device__ __forceinline__ void do_mfma32h(bf16x8 (&af)[4], bf16x8 (&bfr)[4],
                                           f32x16 (&acc)[2][2])
{
    __builtin_amdgcn_s_setprio(1);
    #pragma unroll
    for (int ks = 0; ks < 4; ++ks)
        acc[MI][NJ] = __builtin_amdgcn_mfma_f32_32x32x16_bf16(
            af[ks], bfr[ks], acc[MI][NJ], 0, 0, 0);
    __builtin_amdgcn_s_setprio(0);
}

#define WAITBAR(N) do { \
    asm volatile("s_waitcnt vmcnt(" #N ")" ::: "memory"); \
    __builtin_amdgcn_s_barrier(); } while (0)

// T1 XCD swizzle: bid -> tile, contiguous tile chunk per XCD (nwg % 8 == 0).
// Tiles linearized col-fastest (tile = row*ncol + col) so a chunk shares
// A-row-panels within one XCD's L2.
__device__ __forceinline__ void xcd_tile(int ncol, int& row, int& col)
{
    int q    = gridDim.x >> 3;
    int tile = (blockIdx.x & 7) * q + (blockIdx.x >> 3);
    row = tile / ncol;
    col = tile - row * ncol;
}

// ---------------------------------------------------------------------------
// 256x256 tile, BK=64, 8 waves (2x4), 4-phase counted-vmcnt schedule.
// EPI 0: params: bf16 Cb[m*PST+n]
// EPI 2: out:    Cf[m*N+n] = acc + e0[n] * bf2f(eb[m*N+n])
// 1D grid + T1 XCD swizzle.
// ---------------------------------------------------------------------------
template <int EPI>
__global__ __launch_bounds__(512, 2)
void gemm8p(const bf16_t* __restrict__ A, const bf16_t* __restrict__ B,
            int N, int K, int NT, int ncol,
            bf16_t* __restrict__ Cb, float* __restrict__ Cf,
            const float* __restrict__ e0, const bf16_t* __restrict__ eb)
{
    extern __shared__ __align__(16) char smem_raw[];
    bf16_t* lds = (bf16_t*)smem_raw;

    const int tid  = threadIdx.x;
    const int lane = tid & 63;
    const int wid  = tid >> 6;
    const int wm   = wid >> 2;
    const int wn   = wid & 3;
    const int l31  = lane & 31;
    const int kh   = lane >> 5;
    int trow, tcol;
    xcd_tile(ncol, trow, tcol);
    const int row0 = trow * 256;
    const int col0 = tcol * 256;
    const int lrow = lane >> 3;
    const int cswz = 8 * ((lane & 7) ^ lrow);

    f32x16 acc[4][2];
    #pragma unroll
    for (int i = 0; i < 4; ++i)
        #pragma unroll
        for (int j = 0; j < 2; ++j)
            #pragma unroll
            for (int g = 0; g < 16; ++g) acc[i][j][g] = 0.f;

    stage_slabA(A, lds, 0,     row0, K, 0, 0, wid, lrow, cswz);
    stage_slabB(B, lds, 16384, col0, K, 0, 0, wid, lrow, cswz);
    stage_slabB(B, lds, 16384, col0, K, 0, 1, wid, lrow, cswz);
    stage_slabA(A, lds, 0,     row0, K, 0, 1, wid, lrow, cswz);

    for (int kt = 0; kt < NT; ++kt) {
        const int cur = kt & 1, nxt = cur ^ 1;
        const int Abase = cur * 32768, Bbase = cur * 32768 + 16384;
        const int An = nxt * 32768,   Bn = nxt * 32768 + 16384;
        const int kc = (kt + 1 < NT ? kt + 1 : kt) * 64;

        bf16x8 af[2][4], bfr[4];

        WAITBAR(4);
        load_fragsA32<0>(lds, Abase, wm, l31, kh, af);
        load_fragsB32<0>(lds, Bbase, wn, l31, kh, bfr);
        stage_slabA(A, lds, An, row0, K, kc, 0, wid, lrow, cswz);
        do_mfma32<0, 0>(af, bfr, acc);

        WAITBAR(4);
        load_fragsB32<1>(lds, Bbase, wn, l31, kh, bfr);
        stage_slabB(B, lds, Bn, col0, K, kc, 0, wid, lrow, cswz);
        do_mfma32<0, 1>(af, bfr, acc);

        WAITBAR(4);
        load_fragsA32<1>(lds, Abase, wm, l31, kh, af);
        stage_slabB(B, lds, Bn, col0, K, kc, 1, wid, lrow, cswz);
        do_mfma32<1, 1>(af, bfr, acc);

        load_fragsB32<0>(lds, Bbase, wn, l31, kh, bfr);
        stage_slabA(A, lds, An, row0, K, kc, 1, wid, lrow, cswz);
        do_mfma32<1, 0>(af, bfr, acc);
    }

    // epilogue: 32x32 D map col=lane&31, row=(rg&3)+8*(rg>>2)+4*(lane>>5)
    #pragma unroll
    for (int mi = 0; mi < 4; ++mi) {
        #pragma unroll
        for (int nj = 0; nj < 2; ++nj) {
            #pragma unroll
            for (int rg = 0; rg < 16; ++rg) {
                int mr = row0 + wm * 128 + mi * 32 + (rg & 3) + 8 * (rg >> 2) + 4 * kh;
                int nc = col0 + wn * 64 + nj * 32 + l31;
                float v = acc[mi][nj][rg];
                if (EPI == 0) {
                    Cb[(size_t)mr * PST + nc] = (bf16_t)v;
                } else {
                    float xc = (float)eb[(size_t)mr * N + nc];
                    Cf[(size_t)mr * N + nc] = v + e0[nc] * xc;
                }
            }
        }
    }
}

// ---------------------------------------------------------------------------
// 128x256 tile (GEMM2), BK=64, 8 waves 2x4, counted-vmcnt(2); Bu bf16
// epilogue. 1D grid + T1 XCD swizzle.
// ---------------------------------------------------------------------------
__global__ __launch_bounds__(512, 2)
void gemm8ph(const bf16_t* __restrict__ A, const bf16_t* __restrict__ B,
             int N, int K, int NT, int ncol,
             bf16_t* __restrict__ Bub,
             const float* __restrict__ e0, const bf16_t* __restrict__ eb)
{
    extern __shared__ __align__(16) char smem_raw[];
    bf16_t* lds = (bf16_t*)smem_raw;

    const int tid  = threadIdx.x;
    const int lane = tid & 63;
    const int wid  = tid >> 6;
    const int wm   = wid >> 2;
    const int wn   = wid & 3;
    const int l31  = lane & 31;
    const int kh   = lane >> 5;
    int trow, tcol;
    xcd_tile(ncol, trow, tcol);
    const int row0 = trow * 128;
    const int col0 = tcol * 256;
    const int lrow = lane >> 3;
    const int cswz = 8 * ((lane & 7) ^ lrow);

    f32x16 acc[2][2];
    #pragma unroll
    for (int i = 0; i < 2; ++i)
        #pragma unroll
        for (int j = 0; j < 2; ++j)
            #pragma unroll
            for (int g = 0; g < 16; ++g) acc[i][j][g] = 0.f;

    stage_slabA128(A, lds, 0,    row0, K, 0, wid, lrow, cswz);
    stage_slabB(B, lds, 8192, col0, K, 0, 0, wid, lrow, cswz);
    stage_slabB(B, lds, 8192, col0, K, 0, 1, wid, lrow, cswz);

    for (int kt = 0; kt < NT; ++kt) {
        const int cur = kt & 1, nxt = cur ^ 1;
        const int Abase = cur * 24576, Bbase = cur * 24576 + 8192;
        const int An = nxt * 24576,   Bn = nxt * 24576 + 8192;
        const int kc = (kt + 1 < NT ? kt + 1 : kt) * 64;

        bf16x8 af[4], bfr[4];

        WAITBAR(2);
        load_fragsA32h<0>(lds, Abase, wm, l31, kh, af);
        load_fragsB32<0>(lds, Bbase, wn, l31, kh, bfr);
        stage_slabA128(A, lds, An, row0, K, kc, wid, lrow, cswz);
        do_mfma32h<0, 0>(af, bfr, acc);

        WAITBAR(2);
        load_fragsB32<1>(lds, Bbase, wn, l31, kh, bfr);
        stage_slabB(B, lds, Bn, col0, K, kc, 0, wid, lrow, cswz);
        do_mfma32h<0, 1>(af, bfr, acc);

        load_fragsA32h<1>(lds, Abase, wm, l31, kh, af);
        stage_slabB(B, lds, Bn, col0, K, kc, 1, wid, lrow, cswz);
        do_mfma32h<1, 1>(af, bfr, acc);

        load_fragsB32<0>(lds, Bbase, wn, l31, kh, bfr);
        do_mfma32h<1, 0>(af, bfr, acc);
    }

    #pragma unroll
    for (int mi = 0; mi < 2; ++mi) {
        #pragma unroll
        for (int nj = 0; nj < 2; ++nj) {
            #pragma unroll
            for (int rg = 0; rg < 16; ++rg) {
                int mr = row0 + wm * 64 + mi * 32 + (rg & 3) + 8 * (rg >> 2) + 4 * kh;
                int nc = col0 + wn * 64 + nj * 32 + l31;
                float Bm = (float)eb[(size_t)mr * PST + nc];
                Bub[(size_t)mr * N + nc] = (bf16_t)(e0[mr] * Bm * acc[mi][nj][rg]);
            }
        }
    }
}

// ---------------------------------------------------------------------------
// chunked scan: h[l] = a[l]*h[l-1] + u[l],  a = exp(-exp(A_log[s]) * delta[l])
// ---------------------------------------------------------------------------
__global__ __launch_bounds__(256)
void scan_pass1(const bf16_t* __restrict__ Bu, const float* __restrict__ delta,
                const float* __restrict__ A_log,
                float* __restrict__ cP, float* __restrict__ cH)
{
    int s = blockIdx.x * 256 + threadIdx.x;
    int c = blockIdx.y;
    int b = blockIdx.z;
    float Acoef = -expf(A_log[s]);
    float P = 1.f, h = 0.f;
    int mbase = b * L + c * CL;
    for (int t = 0; t < CL; ++t) {
        float a = __expf(Acoef * delta[mbase + t]);
        float u = (float)Bu[(size_t)(mbase + t) * S + s];
        h = fmaf(a, h, u);
        P *= a;
    }
    int id = b * S + s;
    cP[(size_t)id * NCH + c] = P;
    cH[(size_t)id * NCH + c] = h;
}

__global__ __launch_bounds__(256)
void scan_pass2(const float* __restrict__ cP, const float* __restrict__ cH,
                float* __restrict__ init)
{
    int id = blockIdx.x * 256 + threadIdx.x;
    if (id < Bb * S) {
        float h = 0.f;
        for (int c = 0; c < NCH; ++c) {
            init[(size_t)id * NCH + c] = h;
            h = fmaf(cP[(size_t)id * NCH + c], h, cH[(size_t)id * NCH + c]);
        }
    }
}

__global__ __launch_bounds__(256)
void scan_pass3(const bf16_t* __restrict__ Bu, const float* __restrict__ delta,
                const bf16_t* __restrict__ params_bf,
                const float* __restrict__ A_log,
                const float* __restrict__ init, bf16_t* __restrict__ hmod)
{
    int s = blockIdx.x * 256 + threadIdx.x;
    int c = blockIdx.y;
    int b = blockIdx.z;
    float Acoef = -expf(A_log[s]);
    float h = init[(size_t)(b * S + s) * NCH + c];
    int mbase = b * L + c * CL;
    for (int t = 0; t < CL; ++t) {
        int m = mbase + t;
        float a = __expf(Acoef * delta[m]);
        float u = (float)Bu[(size_t)m * S + s];
        h = fmaf(a, h, u);
        float Cm = (float)params_bf[(size_t)m * PST + S + s];
        hmod[(size_t)m * S + s] = (bf16_t)(Cm * h);
    }
}

// ---------------------------------------------------------------------------
extern "C" void kernel_launch(void* const* d_in, const int* in_sizes, int n_in,
                              void* d_out, int out_size, void* d_ws, size_t ws_size,
                              hipStream_t stream)
{
    const float* x        = (const float*)d_in[0];
    const float* Wxproj   = (const float*)d_in[1];
    const float* Winproj  = (const float*)d_in[2];
    const float* Woutproj = (const float*)d_in[3];
    const float* conv_w   = (const float*)d_in[4];
    const float* conv_b   = (const float*)d_in[5];
    const float* A_log    = (const float*)d_in[6];
    const float* Dvec     = (const float*)d_in[7];
    float* out = (float*)d_out;

    // fp32 workspace
    float* ws_delta = (float*)d_ws;                       // M
    float* ws_dpart = ws_delta + M;                       // M*4
    float* ws_cP    = ws_dpart + (size_t)M * 4;           // Bb*S*NCH
    float* ws_cH    = ws_cP + (size_t)Bb * S * NCH;
    float* ws_init  = ws_cH + (size_t)Bb * S * NCH;
    // bf16 workspace
    bf16_t* Bu_bf     = (bf16_t*)(ws_init + (size_t)Bb * S * NCH); // M*S
    bf16_t* params_bf = Bu_bf + (size_t)M * S;            // M*PST
    bf16_t* x_bf      = params_bf + (size_t)M * PST;      // M*Dm
    bf16_t* hmod_bf   = x_bf;                             // M*S (alias; x_bf dead after GEMM1)
    bf16_t* xconv_bf  = x_bf + (size_t)M * Dm;            // M*Dm
    bf16_t* Wx_bf     = xconv_bf + (size_t)M * Dm;        // PST*Dm
    bf16_t* Win_bf    = Wx_bf + (size_t)PST * Dm;         // S*Dm
    bf16_t* Wout_bf   = Win_bf + (size_t)S * Dm;          // Dm*S

    hipFuncSetAttribute((const void*)gemm8p<0>,
                        hipFuncAttributeMaxDynamicSharedMemorySize, 131072);
    hipFuncSetAttribute((const void*)gemm8p<2>,
                        hipFuncAttributeMaxDynamicSharedMemorySize, 131072);
    hipFuncSetAttribute((const void*)gemm8ph,
                        hipFuncAttributeMaxDynamicSharedMemorySize, 98304);

    // 1. x -> bf16 (pure stream)
    long x8 = (long)M * Dm / 8;
    f2b_kernel<<<(x8 + 255) / 256, 256, 0, stream>>>(x, x_bf, x8, (long)M * Dm);

    // 2. all weight conversions in one launch
    wcvt_kernel<<<2048, 256, 0, stream>>>(Wxproj, Winproj, Woutproj,
                                          Wx_bf, Win_bf, Wout_bf);

    // 3. conv on bf16 x + fused delta partial dot
    conv_bf8<<<Bb * NTC, 256, 0, stream>>>(
        x_bf, conv_w, conv_b, Wxproj + (size_t)(2 * S) * Dm, xconv_bf, ws_dpart);

    // 4. delta = softplus(sum of partials)
    delta_reduce<<<M / 256, 256, 0, stream>>>(ws_dpart, ws_delta);

    // 5. GEMM1: params = x @ Wxproj[0:1024]^T   (256 tiles, XCD-swizzled)
    gemm8p<0><<<(M / 256) * (PST / 256), 512, 131072, stream>>>(
        x_bf, Wx_bf, PST, Dm, Dm / 64, PST / 256,
        params_bf, nullptr, nullptr, nullptr);

    // 6. GEMM2: Bu(bf16) = delta * Bmat * (x_conv @ Winproj^T)  (256 tiles)
    gemm8ph<<<(M / 128) * (S / 256), 512, 98304, stream>>>(
        xconv_bf, Win_bf, S, Dm, Dm / 64, S / 256,
        Bu_bf, ws_delta, params_bf);

    // 7. chunked scan; h_mod = Cmat*h -> bf16
    dim3 gs(S / 256, NCH, Bb);
    scan_pass1<<<gs, 256, 0, stream>>>(Bu_bf, ws_delta, A_log, ws_cP, ws_cH);
    scan_pass2<<<(Bb * S) / 256, 256, 0, stream>>>(ws_cP, ws_cH, ws_init);
    scan_pass3<<<gs, 256, 0, stream>>>(Bu_bf, ws_delta, params_bf, A_log,
                                       ws_init, hmod_bf);

    // 8. GEMM3: out = h_mod @ Woutproj^T + D * x_conv   (512 tiles, swizzled)
    gemm8p<2><<<(M / 256) * (Dm / 256), 512, 131072, stream>>>(
        hmod_bf, Wout_bf, Dm, S, S / 64, Dm / 256,
        nullptr, out, Dvec, xconv_bf);
}